// Round 27
// baseline (301.357 us; speedup 1.0000x reference)
//
#include <hip/hip_runtime.h>
#include <hip/hip_bf16.h>
#include <hip/hip_fp16.h>

#define S_LEN 2048
#define BATCH 2
#define DIM 128
#define NH 8
#define HD 1024
#define QL 5
#define KKTOT 640   // DIM*QL
#define OCH 2048
#define MAXNNZ 384

typedef _Float16 hv2 __attribute__((ext_vector_type(2)));
typedef _Float16 f16x8 __attribute__((ext_vector_type(8)));
typedef float f32x4 __attribute__((ext_vector_type(4)));

#if defined(__has_builtin)
#  if __has_builtin(__builtin_amdgcn_fdot2)
#    define USE_FDOT2 1
#  endif
#endif
#ifndef USE_FDOT2
#  define USE_FDOT2 0
#endif

__device__ __forceinline__ hv2 u2h(unsigned u) {
    union { unsigned u; hv2 h; } c; c.u = u; return c.h;
}
__device__ __forceinline__ float dot2acc(unsigned a, unsigned b, float acc) {
#if USE_FDOT2
    return __builtin_amdgcn_fdot2(u2h(a), u2h(b), acc, false);
#else
    hv2 ha = u2h(a), hb = u2h(b);
    return acc + (float)ha[0] * (float)hb[0] + (float)ha[1] * (float)hb[1];
#endif
}

// ---------------- fused preprocessing: x->fp16, w_qk->bt16 (t-major), w_v/w_proj transpose
__global__ void k_prep(const float* __restrict__ x, const float* __restrict__ w_qk,
                       const float* __restrict__ wv, const float* __restrict__ wp,
                       _Float16* __restrict__ x16, _Float16* __restrict__ bt,
                       _Float16* __restrict__ wvt, _Float16* __restrict__ wpt) {
    int i = blockIdx.x * 256 + threadIdx.x;
    if (i < OCH * KKTOT) {                       // bt16[o][k], k = t*128+i
        int o = i / KKTOT, k = i % KKTOT;
        int t = k >> 7, ii = k & 127;
        bt[i] = (_Float16)w_qk[(size_t)o * KKTOT + ii * QL + t];
        return;
    }
    i -= OCH * KKTOT;
    if (i < BATCH * S_LEN * DIM) {               // x16
        x16[i] = (_Float16)x[i];
        return;
    }
    i -= BATCH * S_LEN * DIM;
    if (i < HD * DIM) {                          // wvt[c][k] = wv[k][c]
        int c = i >> 7, k = i & 127;
        wvt[i] = (_Float16)wv[(size_t)k * HD + c];
        return;
    }
    i -= HD * DIM;
    if (i < DIM * HD) {                          // wpt[c][k] = wp[k][c]
        int c = i >> 10, k = i & 1023;
        wpt[i] = (_Float16)wp[(size_t)k * DIM + c];
    }
}

// ---------------- compact mask rows to CSR (u16 indices)
__global__ void k_mask_csr(const float* __restrict__ mask, unsigned* __restrict__ cnt,
                           unsigned short* __restrict__ idx) {
    __shared__ unsigned s_base;
    __shared__ unsigned s_wcnt[4];
    int r = blockIdx.x;
    int tid = threadIdx.x;
    int lane = tid & 63;
    int w = tid >> 6;
    if (tid == 0) s_base = 0;
    __syncthreads();
    for (int c0 = 0; c0 < S_LEN; c0 += 256) {
        int c = c0 + tid;
        bool act = mask[(size_t)r * S_LEN + c] > 0.5f;
        unsigned long long bal = __ballot(act);
        if (lane == 0) s_wcnt[w] = (unsigned)__popcll(bal);
        __syncthreads();
        unsigned off = s_base;
        for (int i = 0; i < w; i++) off += s_wcnt[i];
        off += (unsigned)__popcll(bal & ((1ull << lane) - 1ull));
        if (act && off < MAXNNZ) idx[r * MAXNNZ + off] = (unsigned short)c;
        __syncthreads();
        if (tid == 0) s_base += s_wcnt[0] + s_wcnt[1] + s_wcnt[2] + s_wcnt[3];
        __syncthreads();
    }
    if (tid == 0) cnt[r] = (s_base < MAXNNZ) ? s_base : MAXNNZ;
}

// ---------------- register-MFMA GEMM: C[4096][NN] = A(x16/im2col) x Bt^T + bias
template<bool CONV, int KSTEPS, int NN, typename OutT>
__global__ void __launch_bounds__(256) k_gemm16(const _Float16* __restrict__ A,
                                                const _Float16* __restrict__ Bt,
                                                const float* __restrict__ bias,
                                                OutT* __restrict__ C) {
    const int K = KSTEPS * 32;
    int tid = threadIdx.x;
    int lane = tid & 63, wave = tid >> 6;
    int wr = wave >> 1, wc = wave & 1;
    int l15 = lane & 15, lk = lane >> 4;
    int rbase = blockIdx.x * 64;            // global row base
    int batch = rbase >> 11;
    int s0 = rbase & 2047;                  // batch-local row base
    f32x4 acc[2][2] = {};
    for (int ks = 0; ks < KSTEPS; ks++) {
        int t = CONV ? (ks >> 2) : 0;
        int i0 = CONV ? ((ks & 3) * 32) : (ks * 32);
        f16x8 afr[2], bfr[2];
#pragma unroll
        for (int a = 0; a < 2; a++) {
            int srow = s0 + wr * 32 + a * 16 + l15;
            int sx = CONV ? (srow - (QL - 1) + t) : srow;
            int sclamp = sx < 0 ? 0 : sx;
            f16x8 av = *reinterpret_cast<const f16x8*>(
                A + ((size_t)(batch * S_LEN + sclamp)) * (CONV ? DIM : (K)) + i0 + lk * 8);
            if (CONV && sx < 0) av = f16x8{0, 0, 0, 0, 0, 0, 0, 0};
            afr[a] = av;
        }
#pragma unroll
        for (int bb = 0; bb < 2; bb++) {
            int col = blockIdx.y * 64 + wc * 32 + bb * 16 + l15;
            bfr[bb] = *reinterpret_cast<const f16x8*>(Bt + (size_t)col * K + ks * 32 + lk * 8);
        }
#pragma unroll
        for (int a = 0; a < 2; a++)
#pragma unroll
            for (int bb = 0; bb < 2; bb++)
                acc[a][bb] = __builtin_amdgcn_mfma_f32_16x16x32_f16(afr[a], bfr[bb], acc[a][bb], 0, 0, 0);
    }
#pragma unroll
    for (int a = 0; a < 2; a++)
#pragma unroll
        for (int bb = 0; bb < 2; bb++) {
            int col = blockIdx.y * 64 + wc * 32 + bb * 16 + l15;
            float bs = bias[col];
#pragma unroll
            for (int j = 0; j < 4; j++) {
                int row = rbase + wr * 32 + a * 16 + lk * 4 + j;   // C/D: row=(lane>>4)*4+j, col=lane&15
                C[(size_t)row * NN + col] = (OutT)(acc[a][bb][j] + bs);
            }
        }
}

// ---------------- sparse attention + entmax15 (Newton-8 on wave 0), fp16 out
// Phase 1: 4-col unroll (16 loads in flight); PV: quad-slot pk-fma unroll.
__global__ void __launch_bounds__(256) k_attn(const _Float16* __restrict__ qk16,
                                              const _Float16* __restrict__ val16,
                                              const unsigned* __restrict__ cnt,
                                              const unsigned short* __restrict__ idxbuf,
                                              _Float16* __restrict__ attout) {
    __shared__ float ssc[MAXNNZ];
    __shared__ unsigned short sidx[MAXNNZ];
    __shared__ float pvs[16][136];
    int l = blockIdx.x;
    int bid = (l & 7) * 4096 + (l >> 3);   // XCD swizzle (32768 = 8 * 4096, bijective)
    int r = bid & (S_LEN - 1);
    int h = (bid >> 11) & (NH - 1);
    int b = bid >> 14;
    int tid = threadIdx.x;
    int lane = tid & 63;
    int wave = tid >> 6;
    int n = (int)cnt[r];
    const float scale = 0.08838834764831843f;  // 1/sqrt(128)

    for (int j = tid; j < n; j += 256) sidx[j] = idxbuf[r * MAXNNZ + j];
    __syncthreads();

    // ---- phase 1: scores; fp16 q in registers, 4 columns per iteration (MLP)
    {
        int grp = tid >> 2;          // 0..63
        int ll  = tid & 3;           // lane within group
        const uint4* q16 = reinterpret_cast<const uint4*>(
                               qk16 + ((size_t)(b * S_LEN + r)) * OCH + h * 128);
        uint4 qreg[4];
#pragma unroll
        for (int i = 0; i < 4; i++) qreg[i] = q16[i * 4 + ll];
        const _Float16* kbase = qk16 + (size_t)b * S_LEN * OCH + HD + h * 128;
        for (int j0 = grp; j0 < n; j0 += 256) {
            int j1 = j0 + 64, j2 = j0 + 128, j3 = j0 + 192;
            int c1 = j1 < n ? j1 : j0;      // clamped (load valid, store predicated)
            int c2 = j2 < n ? j2 : j0;
            int c3 = j3 < n ? j3 : j0;
            const uint4* kp0 = reinterpret_cast<const uint4*>(kbase + (size_t)sidx[j0] * OCH);
            const uint4* kp1 = reinterpret_cast<const uint4*>(kbase + (size_t)sidx[c1] * OCH);
            const uint4* kp2 = reinterpret_cast<const uint4*>(kbase + (size_t)sidx[c2] * OCH);
            const uint4* kp3 = reinterpret_cast<const uint4*>(kbase + (size_t)sidx[c3] * OCH);
            float p0 = 0.f, p1 = 0.f, p2 = 0.f, p3 = 0.f;
#pragma unroll
            for (int i = 0; i < 4; i++) {
                uint4 kv0 = kp0[i * 4 + ll];
                uint4 kv1 = kp1[i * 4 + ll];
                uint4 kv2 = kp2[i * 4 + ll];
                uint4 kv3 = kp3[i * 4 + ll];
                const unsigned* ka0 = reinterpret_cast<const unsigned*>(&kv0);
                const unsigned* ka1 = reinterpret_cast<const unsigned*>(&kv1);
                const unsigned* ka2 = reinterpret_cast<const unsigned*>(&kv2);
                const unsigned* ka3 = reinterpret_cast<const unsigned*>(&kv3);
                const unsigned* qa = reinterpret_cast<const unsigned*>(&qreg[i]);
#pragma unroll
                for (int c = 0; c < 4; c++) {
                    p0 = dot2acc(qa[c], ka0[c], p0);
                    p1 = dot2acc(qa[c], ka1[c], p1);
                    p2 = dot2acc(qa[c], ka2[c], p2);
                    p3 = dot2acc(qa[c], ka3[c], p3);
                }
            }
            p0 += __shfl_xor(p0, 1, 64);
            p1 += __shfl_xor(p1, 1, 64);
            p2 += __shfl_xor(p2, 1, 64);
            p3 += __shfl_xor(p3, 1, 64);
            p0 += __shfl_xor(p0, 2, 64);
            p1 += __shfl_xor(p1, 2, 64);
            p2 += __shfl_xor(p2, 2, 64);
            p3 += __shfl_xor(p3, 2, 64);
            if (ll == 0) {
                ssc[j0] = p0 * scale;
                if (j1 < n) ssc[j1] = p1 * scale;
                if (j2 < n) ssc[j2] = p2 * scale;
                if (j3 < n) ssc[j3] = p3 * scale;
            }
        }
    }
    __syncthreads();

    // ---- phase 2: entmax tau on wave 0 — fused max + Newton-from-below (8 it)
    if (wave == 0) {
        float xl[6];
        float mx = -3.0e38f;
#pragma unroll
        for (int l2 = 0; l2 < 6; l2++) {
            int j = lane + 64 * l2;
            xl[l2] = (j < n) ? ssc[j] * 0.5f : -3.0e38f;
            mx = fmaxf(mx, xl[l2]);
        }
#pragma unroll
        for (int off = 32; off >= 1; off >>= 1) mx = fmaxf(mx, __shfl_xor(mx, off, 64));
        float tau = mx - 1.f;
        for (int it = 0; it < 8; it++) {
            float s1 = 0.f, s2 = 0.f;
#pragma unroll
            for (int l2 = 0; l2 < 6; l2++) {
                float d = fmaxf(xl[l2] - tau, 0.f);
                s1 += d;
                s2 += d * d;
            }
#pragma unroll
            for (int off = 32; off >= 1; off >>= 1) {
                s1 += __shfl_xor(s1, off, 64);
                s2 += __shfl_xor(s2, off, 64);
            }
            tau += (s2 - 1.f) / (2.f * s1);
        }
#pragma unroll
        for (int l2 = 0; l2 < 6; l2++) {
            int j = lane + 64 * l2;
            if (j < n) {
                float d = fmaxf(xl[l2] - tau, 0.f);
                ssc[j] = d * d;
            }
        }
    }
    __syncthreads();

    // ---- phase 3: PV in packed fp16 (v_pk_fma_f16), quad-slot unroll
    {
        int slot = tid >> 4;         // 0..15
        int dg   = tid & 15;         // dims dg*8..dg*8+7
        const uint4* vbase = reinterpret_cast<const uint4*>(
                                 val16 + (size_t)b * S_LEN * HD + h * 128) + dg;
        hv2 accA[4] = {}, accB[4] = {}, accC[4] = {}, accD[4] = {};
        int j = slot;
        for (; j + 48 < n; j += 64) {
            _Float16 wA = (_Float16)ssc[j];
            _Float16 wB = (_Float16)ssc[j + 16];
            _Float16 wC = (_Float16)ssc[j + 32];
            _Float16 wD = (_Float16)ssc[j + 48];
            hv2 wA2 = {wA, wA}, wB2 = {wB, wB}, wC2 = {wC, wC}, wD2 = {wD, wD};
            uint4 vvA = vbase[(size_t)sidx[j] << 7];
            uint4 vvB = vbase[(size_t)sidx[j + 16] << 7];
            uint4 vvC = vbase[(size_t)sidx[j + 32] << 7];
            uint4 vvD = vbase[(size_t)sidx[j + 48] << 7];
            const hv2* vaA = reinterpret_cast<const hv2*>(&vvA);
            const hv2* vaB = reinterpret_cast<const hv2*>(&vvB);
            const hv2* vaC = reinterpret_cast<const hv2*>(&vvC);
            const hv2* vaD = reinterpret_cast<const hv2*>(&vvD);
#pragma unroll
            for (int k = 0; k < 4; k++) {
                accA[k] += wA2 * vaA[k];    // v_pk_fma_f16
                accB[k] += wB2 * vaB[k];
                accC[k] += wC2 * vaC[k];
                accD[k] += wD2 * vaD[k];
            }
        }
        for (; j < n; j += 16) {
            _Float16 wA = (_Float16)ssc[j];
            hv2 wA2 = {wA, wA};
            uint4 vv = vbase[(size_t)sidx[j] << 7];
            const hv2* va = reinterpret_cast<const hv2*>(&vv);
#pragma unroll
            for (int k = 0; k < 4; k++) accA[k] += wA2 * va[k];
        }
#pragma unroll
        for (int k = 0; k < 4; k++) {
            accA[k] += accB[k];
            accC[k] += accD[k];
        }
        float4 v0, v1;
        v0.x = (float)accA[0][0] + (float)accC[0][0];
        v0.y = (float)accA[0][1] + (float)accC[0][1];
        v0.z = (float)accA[1][0] + (float)accC[1][0];
        v0.w = (float)accA[1][1] + (float)accC[1][1];
        v1.x = (float)accA[2][0] + (float)accC[2][0];
        v1.y = (float)accA[2][1] + (float)accC[2][1];
        v1.z = (float)accA[3][0] + (float)accC[3][0];
        v1.w = (float)accA[3][1] + (float)accC[3][1];
        *reinterpret_cast<float4*>(&pvs[slot][dg * 8]) = v0;
        *reinterpret_cast<float4*>(&pvs[slot][dg * 8 + 4]) = v1;
    }
    __syncthreads();
    if (tid < 128) {
        float a = 0.f;
#pragma unroll
        for (int s = 0; s < 16; s++) a += pvs[s][tid];
        attout[((size_t)(b * S_LEN + r)) * HD + h * 128 + tid] = (_Float16)a;
    }
}

extern "C" void kernel_launch(void* const* d_in, const int* in_sizes, int n_in,
                              void* d_out, int out_size, void* d_ws, size_t ws_size,
                              hipStream_t stream) {
    const float* x      = (const float*)d_in[0];
    const float* mask   = (const float*)d_in[1];
    const float* w_qk   = (const float*)d_in[2];
    const float* b_qk   = (const float*)d_in[3];
    const float* w_v    = (const float*)d_in[4];
    const float* b_v    = (const float*)d_in[5];
    const float* w_proj = (const float*)d_in[6];
    const float* b_proj = (const float*)d_in[7];
    float* out = (float*)d_out;     // reference output dtype is FLOAT32

    char* ws = (char*)d_ws;
    _Float16*       x16   = (_Float16*)(ws + 0);         //  1,048,576 B
    _Float16*       qk16  = (_Float16*)(ws + 1048576);   // 16,777,216 B
    _Float16*       val16 = (_Float16*)(ws + 17825792);  //  8,388,608 B
    _Float16*       bt16  = (_Float16*)(ws + 26214400);  //  2,621,440 B  [2048][640]
    _Float16*       wvt   = (_Float16*)(ws + 28835840);  //    262,144 B  [1024][128]
    _Float16*       wpt   = (_Float16*)(ws + 29097984);  //    262,144 B  [128][1024]
    unsigned*       cnt   = (unsigned*)(ws + 29360128);  //      8,192 B
    unsigned short* idx   = (unsigned short*)(ws + 29368320);  // 1,572,864 B (u16)
    _Float16*       ao16  = (_Float16*)(ws + 32514048);  //  8,388,608 B -> end 40,902,656

    hipLaunchKernelGGL(k_prep, dim3(8192), dim3(256), 0, stream,
                       x, w_qk, w_v, w_proj, x16, bt16, wvt, wpt);
    hipLaunchKernelGGL(k_mask_csr, dim3(S_LEN), dim3(256), 0, stream, mask, cnt, idx);
    hipLaunchKernelGGL((k_gemm16<false, 4, HD, _Float16>), dim3(BATCH * S_LEN / 64, HD / 64), dim3(256), 0, stream,
                       x16, wvt, b_v, val16);
    hipLaunchKernelGGL((k_gemm16<true, 20, OCH, _Float16>), dim3(BATCH * S_LEN / 64, OCH / 64), dim3(256), 0, stream,
                       x16, bt16, b_qk, qk16);
    hipLaunchKernelGGL(k_attn, dim3(BATCH * NH * S_LEN), dim3(256), 0, stream, qk16, val16, cnt, idx, ao16);
    hipLaunchKernelGGL((k_gemm16<false, 32, DIM, float>), dim3(BATCH * S_LEN / 64, DIM / 64), dim3(256), 0, stream,
                       ao16, wpt, b_proj, out);
}

// Round 28
// 278.253 us; speedup vs baseline: 1.0830x; 1.0830x over previous
//
#include <hip/hip_runtime.h>
#include <hip/hip_bf16.h>
#include <hip/hip_fp16.h>

#define S_LEN 2048
#define BATCH 2
#define DIM 128
#define NH 8
#define HD 1024
#define QL 5
#define KKTOT 640   // DIM*QL
#define OCH 2048
#define MAXNNZ 384

typedef _Float16 hv2 __attribute__((ext_vector_type(2)));
typedef _Float16 f16x8 __attribute__((ext_vector_type(8)));
typedef float f32x4 __attribute__((ext_vector_type(4)));

#if defined(__has_builtin)
#  if __has_builtin(__builtin_amdgcn_fdot2)
#    define USE_FDOT2 1
#  endif
#endif
#ifndef USE_FDOT2
#  define USE_FDOT2 0
#endif

__device__ __forceinline__ hv2 u2h(unsigned u) {
    union { unsigned u; hv2 h; } c; c.u = u; return c.h;
}
__device__ __forceinline__ float dot2acc(unsigned a, unsigned b, float acc) {
#if USE_FDOT2
    return __builtin_amdgcn_fdot2(u2h(a), u2h(b), acc, false);
#else
    hv2 ha = u2h(a), hb = u2h(b);
    return acc + (float)ha[0] * (float)hb[0] + (float)ha[1] * (float)hb[1];
#endif
}

// ---------------- fused preprocessing: x->fp16, w_qk->bt16 (t-major), w_v/w_proj transpose
__global__ void k_prep(const float* __restrict__ x, const float* __restrict__ w_qk,
                       const float* __restrict__ wv, const float* __restrict__ wp,
                       _Float16* __restrict__ x16, _Float16* __restrict__ bt,
                       _Float16* __restrict__ wvt, _Float16* __restrict__ wpt) {
    int i = blockIdx.x * 256 + threadIdx.x;
    if (i < OCH * KKTOT) {                       // bt16[o][k], k = t*128+i
        int o = i / KKTOT, k = i % KKTOT;
        int t = k >> 7, ii = k & 127;
        bt[i] = (_Float16)w_qk[(size_t)o * KKTOT + ii * QL + t];
        return;
    }
    i -= OCH * KKTOT;
    if (i < BATCH * S_LEN * DIM) {               // x16
        x16[i] = (_Float16)x[i];
        return;
    }
    i -= BATCH * S_LEN * DIM;
    if (i < HD * DIM) {                          // wvt[c][k] = wv[k][c]
        int c = i >> 7, k = i & 127;
        wvt[i] = (_Float16)wv[(size_t)k * HD + c];
        return;
    }
    i -= HD * DIM;
    if (i < DIM * HD) {                          // wpt[c][k] = wp[k][c]
        int c = i >> 10, k = i & 1023;
        wpt[i] = (_Float16)wp[(size_t)k * DIM + c];
    }
}

// ---------------- compact mask rows to CSR (u16 indices)
__global__ void k_mask_csr(const float* __restrict__ mask, unsigned* __restrict__ cnt,
                           unsigned short* __restrict__ idx) {
    __shared__ unsigned s_base;
    __shared__ unsigned s_wcnt[4];
    int r = blockIdx.x;
    int tid = threadIdx.x;
    int lane = tid & 63;
    int w = tid >> 6;
    if (tid == 0) s_base = 0;
    __syncthreads();
    for (int c0 = 0; c0 < S_LEN; c0 += 256) {
        int c = c0 + tid;
        bool act = mask[(size_t)r * S_LEN + c] > 0.5f;
        unsigned long long bal = __ballot(act);
        if (lane == 0) s_wcnt[w] = (unsigned)__popcll(bal);
        __syncthreads();
        unsigned off = s_base;
        for (int i = 0; i < w; i++) off += s_wcnt[i];
        off += (unsigned)__popcll(bal & ((1ull << lane) - 1ull));
        if (act && off < MAXNNZ) idx[r * MAXNNZ + off] = (unsigned short)c;
        __syncthreads();
        if (tid == 0) s_base += s_wcnt[0] + s_wcnt[1] + s_wcnt[2] + s_wcnt[3];
        __syncthreads();
    }
    if (tid == 0) cnt[r] = (s_base < MAXNNZ) ? s_base : MAXNNZ;
}

// ---------------- register-MFMA GEMM: C[4096][NN] = A(x16/im2col) x Bt^T + bias
template<bool CONV, int KSTEPS, int NN, typename OutT>
__global__ void __launch_bounds__(256) k_gemm16(const _Float16* __restrict__ A,
                                                const _Float16* __restrict__ Bt,
                                                const float* __restrict__ bias,
                                                OutT* __restrict__ C) {
    const int K = KSTEPS * 32;
    int tid = threadIdx.x;
    int lane = tid & 63, wave = tid >> 6;
    int wr = wave >> 1, wc = wave & 1;
    int l15 = lane & 15, lk = lane >> 4;
    int rbase = blockIdx.x * 64;            // global row base
    int batch = rbase >> 11;
    int s0 = rbase & 2047;                  // batch-local row base
    f32x4 acc[2][2] = {};
    for (int ks = 0; ks < KSTEPS; ks++) {
        int t = CONV ? (ks >> 2) : 0;
        int i0 = CONV ? ((ks & 3) * 32) : (ks * 32);
        f16x8 afr[2], bfr[2];
#pragma unroll
        for (int a = 0; a < 2; a++) {
            int srow = s0 + wr * 32 + a * 16 + l15;
            int sx = CONV ? (srow - (QL - 1) + t) : srow;
            int sclamp = sx < 0 ? 0 : sx;
            f16x8 av = *reinterpret_cast<const f16x8*>(
                A + ((size_t)(batch * S_LEN + sclamp)) * (CONV ? DIM : (K)) + i0 + lk * 8);
            if (CONV && sx < 0) av = f16x8{0, 0, 0, 0, 0, 0, 0, 0};
            afr[a] = av;
        }
#pragma unroll
        for (int bb = 0; bb < 2; bb++) {
            int col = blockIdx.y * 64 + wc * 32 + bb * 16 + l15;
            bfr[bb] = *reinterpret_cast<const f16x8*>(Bt + (size_t)col * K + ks * 32 + lk * 8);
        }
#pragma unroll
        for (int a = 0; a < 2; a++)
#pragma unroll
            for (int bb = 0; bb < 2; bb++)
                acc[a][bb] = __builtin_amdgcn_mfma_f32_16x16x32_f16(afr[a], bfr[bb], acc[a][bb], 0, 0, 0);
    }
#pragma unroll
    for (int a = 0; a < 2; a++)
#pragma unroll
        for (int bb = 0; bb < 2; bb++) {
            int col = blockIdx.y * 64 + wc * 32 + bb * 16 + l15;
            float bs = bias[col];
#pragma unroll
            for (int j = 0; j < 4; j++) {
                int row = rbase + wr * 32 + a * 16 + lk * 4 + j;   // C/D: row=(lane>>4)*4+j, col=lane&15
                C[(size_t)row * NN + col] = (OutT)(acc[a][bb][j] + bs);
            }
        }
}

// ---------------- sparse attention + entmax15 (Newton-8 on wave 0), fp16 out
// Phase 1: 2-col unroll; PV: packed v_pk_fma_f16 accumulation, dual-slot.
__global__ void __launch_bounds__(256) k_attn(const _Float16* __restrict__ qk16,
                                              const _Float16* __restrict__ val16,
                                              const unsigned* __restrict__ cnt,
                                              const unsigned short* __restrict__ idxbuf,
                                              _Float16* __restrict__ attout) {
    __shared__ float ssc[MAXNNZ];
    __shared__ unsigned short sidx[MAXNNZ];
    __shared__ float pvs[16][136];
    int l = blockIdx.x;
    int bid = (l & 7) * 4096 + (l >> 3);   // XCD swizzle (32768 = 8 * 4096, bijective)
    int r = bid & (S_LEN - 1);
    int h = (bid >> 11) & (NH - 1);
    int b = bid >> 14;
    int tid = threadIdx.x;
    int lane = tid & 63;
    int wave = tid >> 6;
    int n = (int)cnt[r];
    const float scale = 0.08838834764831843f;  // 1/sqrt(128)

    for (int j = tid; j < n; j += 256) sidx[j] = idxbuf[r * MAXNNZ + j];
    __syncthreads();

    // ---- phase 1: scores; fp16 q in registers, 2 columns per iteration (MLP)
    {
        int grp = tid >> 2;          // 0..63
        int ll  = tid & 3;           // lane within group
        const uint4* q16 = reinterpret_cast<const uint4*>(
                               qk16 + ((size_t)(b * S_LEN + r)) * OCH + h * 128);
        uint4 qreg[4];
#pragma unroll
        for (int i = 0; i < 4; i++) qreg[i] = q16[i * 4 + ll];
        const _Float16* kbase = qk16 + (size_t)b * S_LEN * OCH + HD + h * 128;
        for (int j0 = grp; j0 < n; j0 += 128) {
            int j1 = j0 + 64;
            bool has1 = j1 < n;
            const uint4* kp0 = reinterpret_cast<const uint4*>(kbase + (size_t)sidx[j0] * OCH);
            const uint4* kp1 = has1 ? reinterpret_cast<const uint4*>(kbase + (size_t)sidx[j1] * OCH) : kp0;
            float p0 = 0.f, p1 = 0.f;
#pragma unroll
            for (int i = 0; i < 4; i++) {
                uint4 kv0 = kp0[i * 4 + ll];
                uint4 kv1 = kp1[i * 4 + ll];
                const unsigned* ka0 = reinterpret_cast<const unsigned*>(&kv0);
                const unsigned* ka1 = reinterpret_cast<const unsigned*>(&kv1);
                const unsigned* qa = reinterpret_cast<const unsigned*>(&qreg[i]);
#pragma unroll
                for (int c = 0; c < 4; c++) {
                    p0 = dot2acc(qa[c], ka0[c], p0);
                    p1 = dot2acc(qa[c], ka1[c], p1);
                }
            }
            p0 += __shfl_xor(p0, 1, 64);
            p0 += __shfl_xor(p0, 2, 64);
            p1 += __shfl_xor(p1, 1, 64);
            p1 += __shfl_xor(p1, 2, 64);
            if (ll == 0) {
                ssc[j0] = p0 * scale;
                if (has1) ssc[j1] = p1 * scale;
            }
        }
    }
    __syncthreads();

    // ---- phase 2: entmax tau on wave 0 — fused max + Newton-from-below (8 it)
    if (wave == 0) {
        float xl[6];
        float mx = -3.0e38f;
#pragma unroll
        for (int l2 = 0; l2 < 6; l2++) {
            int j = lane + 64 * l2;
            xl[l2] = (j < n) ? ssc[j] * 0.5f : -3.0e38f;
            mx = fmaxf(mx, xl[l2]);
        }
#pragma unroll
        for (int off = 32; off >= 1; off >>= 1) mx = fmaxf(mx, __shfl_xor(mx, off, 64));
        float tau = mx - 1.f;
        for (int it = 0; it < 8; it++) {
            float s1 = 0.f, s2 = 0.f;
#pragma unroll
            for (int l2 = 0; l2 < 6; l2++) {
                float d = fmaxf(xl[l2] - tau, 0.f);
                s1 += d;
                s2 += d * d;
            }
#pragma unroll
            for (int off = 32; off >= 1; off >>= 1) {
                s1 += __shfl_xor(s1, off, 64);
                s2 += __shfl_xor(s2, off, 64);
            }
            tau += (s2 - 1.f) / (2.f * s1);
        }
#pragma unroll
        for (int l2 = 0; l2 < 6; l2++) {
            int j = lane + 64 * l2;
            if (j < n) {
                float d = fmaxf(xl[l2] - tau, 0.f);
                ssc[j] = d * d;
            }
        }
    }
    __syncthreads();

    // ---- phase 3: PV in packed fp16 (v_pk_fma_f16), dual-slot unroll
    {
        int slot = tid >> 4;         // 0..15
        int dg   = tid & 15;         // dims dg*8..dg*8+7
        const uint4* vbase = reinterpret_cast<const uint4*>(
                                 val16 + (size_t)b * S_LEN * HD + h * 128) + dg;
        hv2 accA[4] = {};
        hv2 accB[4] = {};
        int j = slot;
        for (; j + 16 < n; j += 32) {
            _Float16 wA = (_Float16)ssc[j];
            _Float16 wB = (_Float16)ssc[j + 16];
            hv2 wA2 = {wA, wA};
            hv2 wB2 = {wB, wB};
            uint4 vvA = vbase[(size_t)sidx[j] << 7];
            uint4 vvB = vbase[(size_t)sidx[j + 16] << 7];
            const hv2* vaA = reinterpret_cast<const hv2*>(&vvA);
            const hv2* vaB = reinterpret_cast<const hv2*>(&vvB);
#pragma unroll
            for (int k = 0; k < 4; k++) {
                accA[k] += wA2 * vaA[k];    // v_pk_fma_f16
                accB[k] += wB2 * vaB[k];
            }
        }
        if (j < n) {
            _Float16 wA = (_Float16)ssc[j];
            hv2 wA2 = {wA, wA};
            uint4 vv = vbase[(size_t)sidx[j] << 7];
            const hv2* va = reinterpret_cast<const hv2*>(&vv);
#pragma unroll
            for (int k = 0; k < 4; k++) accA[k] += wA2 * va[k];
        }
        float4 v0, v1;
        v0.x = (float)accA[0][0] + (float)accB[0][0];
        v0.y = (float)accA[0][1] + (float)accB[0][1];
        v0.z = (float)accA[1][0] + (float)accB[1][0];
        v0.w = (float)accA[1][1] + (float)accB[1][1];
        v1.x = (float)accA[2][0] + (float)accB[2][0];
        v1.y = (float)accA[2][1] + (float)accB[2][1];
        v1.z = (float)accA[3][0] + (float)accB[3][0];
        v1.w = (float)accA[3][1] + (float)accB[3][1];
        *reinterpret_cast<float4*>(&pvs[slot][dg * 8]) = v0;
        *reinterpret_cast<float4*>(&pvs[slot][dg * 8 + 4]) = v1;
    }
    __syncthreads();
    if (tid < 128) {
        float a = 0.f;
#pragma unroll
        for (int s = 0; s < 16; s++) a += pvs[s][tid];
        attout[((size_t)(b * S_LEN + r)) * HD + h * 128 + tid] = (_Float16)a;
    }
}

extern "C" void kernel_launch(void* const* d_in, const int* in_sizes, int n_in,
                              void* d_out, int out_size, void* d_ws, size_t ws_size,
                              hipStream_t stream) {
    const float* x      = (const float*)d_in[0];
    const float* mask   = (const float*)d_in[1];
    const float* w_qk   = (const float*)d_in[2];
    const float* b_qk   = (const float*)d_in[3];
    const float* w_v    = (const float*)d_in[4];
    const float* b_v    = (const float*)d_in[5];
    const float* w_proj = (const float*)d_in[6];
    const float* b_proj = (const float*)d_in[7];
    float* out = (float*)d_out;     // reference output dtype is FLOAT32

    char* ws = (char*)d_ws;
    _Float16*       x16   = (_Float16*)(ws + 0);         //  1,048,576 B
    _Float16*       qk16  = (_Float16*)(ws + 1048576);   // 16,777,216 B
    _Float16*       val16 = (_Float16*)(ws + 17825792);  //  8,388,608 B
    _Float16*       bt16  = (_Float16*)(ws + 26214400);  //  2,621,440 B  [2048][640]
    _Float16*       wvt   = (_Float16*)(ws + 28835840);  //    262,144 B  [1024][128]
    _Float16*       wpt   = (_Float16*)(ws + 29097984);  //    262,144 B  [128][1024]
    unsigned*       cnt   = (unsigned*)(ws + 29360128);  //      8,192 B
    unsigned short* idx   = (unsigned short*)(ws + 29368320);  // 1,572,864 B (u16)
    _Float16*       ao16  = (_Float16*)(ws + 32514048);  //  8,388,608 B -> end 40,902,656

    hipLaunchKernelGGL(k_prep, dim3(8192), dim3(256), 0, stream,
                       x, w_qk, w_v, w_proj, x16, bt16, wvt, wpt);
    hipLaunchKernelGGL(k_mask_csr, dim3(S_LEN), dim3(256), 0, stream, mask, cnt, idx);
    hipLaunchKernelGGL((k_gemm16<false, 4, HD, _Float16>), dim3(BATCH * S_LEN / 64, HD / 64), dim3(256), 0, stream,
                       x16, wvt, b_v, val16);
    hipLaunchKernelGGL((k_gemm16<true, 20, OCH, _Float16>), dim3(BATCH * S_LEN / 64, OCH / 64), dim3(256), 0, stream,
                       x16, bt16, b_qk, qk16);
    hipLaunchKernelGGL(k_attn, dim3(BATCH * NH * S_LEN), dim3(256), 0, stream, qk16, val16, cnt, idx, ao16);
    hipLaunchKernelGGL((k_gemm16<false, 32, DIM, float>), dim3(BATCH * S_LEN / 64, DIM / 64), dim3(256), 0, stream,
                       ao16, wpt, b_proj, out);
}